// Round 6
// baseline (320.541 us; speedup 1.0000x reference)
//
#include <hip/hip_runtime.h>
#include <hip/hip_bf16.h>
#include <stdint.h>
#include <math.h>

// Problem constants
#define DD 1024
#define SS 2048
#define BB 4

typedef __bf16 bf16;
typedef __bf16 bf16x8 __attribute__((ext_vector_type(8)));
typedef __bf16 bf16x4 __attribute__((ext_vector_type(4)));
typedef float f32x4 __attribute__((ext_vector_type(4)));

// ---- async global->LDS 16B copy (dest = wave-uniform base + lane*16) ----
__device__ __forceinline__ void gload_lds16(const bf16* g, bf16* l) {
  __builtin_amdgcn_global_load_lds(
      (const __attribute__((address_space(1))) void*)g,
      (__attribute__((address_space(3))) void*)l, 16, 0, 0);
}

// ---- ALL preprocessing in ONE dispatch --------------------------------
__global__ __launch_bounds__(256) void prep_all(
    const float* __restrict__ x, const float* __restrict__ R,
    const float* __restrict__ E, const float* __restrict__ Wv,
    const float* __restrict__ Wq, const float* __restrict__ Wk,
    const float* __restrict__ bq, const float* __restrict__ bk,
    const float* __restrict__ bv, bf16* __restrict__ xb,
    bf16* __restrict__ Rb, bf16* __restrict__ Eb, bf16* __restrict__ Wvb,
    bf16* __restrict__ WqT, bf16* __restrict__ WkT, float* __restrict__ bias,
    float* __restrict__ rowsums) {
  int bid = blockIdx.x;
  int t = threadIdx.x;
  if (bid < 11264) {
    const float* src;
    bf16* dst;
    int base;
    if (bid < 8192) { src = x; dst = xb; base = bid; }
    else if (bid < 9216) { src = R; dst = Rb; base = bid - 8192; }
    else if (bid < 10240) { src = E; dst = Eb; base = bid - 9216; }
    else { src = Wv; dst = Wvb; base = bid - 10240; }
    int i = (base * 256 + t) * 4;
    float4 v = *(const float4*)(src + i);
    bf16x4 o;
    o.x = (bf16)v.x; o.y = (bf16)v.y; o.z = (bf16)v.z; o.w = (bf16)v.w;
    *(bf16x4*)(dst + i) = o;
  } else if (bid < 13312) {
    int r2 = bid - 11264;
    const float* src = (r2 >= 1024) ? Wk : Wq;
    bf16* dst = (r2 >= 1024) ? WkT : WqT;
    int rem = r2 & 1023;
    int bx = rem & 31, by = rem >> 5;
    __shared__ float tile[32][33];
    int tx = t & 31, ty = t >> 5;
    int xcol = bx * 32 + tx;
    int y0 = by * 32;
    for (int r = ty; r < 32; r += 8)
      tile[r][tx] = src[(y0 + r) * DD + xcol];
    __syncthreads();
    int dx = by * 32 + tx;
    int dy0 = bx * 32;
    for (int r = ty; r < 32; r += 8)
      dst[(dy0 + r) * DD + dx] = (bf16)tile[tx][r];
  } else if (bid < 16384) {
    int e = bid - 13312;  // 0..3071
    if (e >= 2048) { if (t == 0) bias[e] = bv[e - 2048]; return; }
    const float* M = (e < 1024) ? R : E;
    const float* bb = (e < 1024) ? bq : bk;
    int row = e & 1023;
    float s = 0.f;
    for (int f = t; f < DD; f += 256) s += M[row * DD + f] * bb[f];
    for (int o = 32; o >= 1; o >>= 1) s += __shfl_xor(s, o, 64);
    __shared__ float red[4];
    if ((t & 63) == 0) red[t >> 6] = s;
    __syncthreads();
    if (t == 0) bias[e] = red[0] + red[1] + red[2] + red[3];
  } else {
    int idx = (bid - 16384) * 256 + t;  // 0..8191
    rowsums[idx] = 0.f;
  }
}

// =====================================================================
// gemm256_8ph: QKV on the m201 8-phase template. 256x256 tile, BK=64,
// 8 waves (2Mx4N, per-wave 128x64, acc[8][4]), 128 KiB DYNAMIC LDS:
//   A: buf*32KB (half h: +16KB... element offsets below), B: +64KB.
// Subtile = [128 rows][64 k] bf16 (16 KB), XOR swizzle: LDS chunk c of row
// r holds global chunk c^(r&7) (2-way on banks = free). Staged as 2
// gload_lds ops (64 rows each), inverse-swizzled source (rule #21).
// Iteration = 2 K-tiles (kt even->buf0, odd->buf1), 8 phases:
//  p1: rd A(b0)ks0 x8 + B(b0)ks0 x4 ; STG B0(kt+1)  | bar lgkm MFMA(mh0,ks0) bar
//  p2: rd A(b0)ks1 x8 + B(b0)ks1 x4 ; STG B1(kt+1)  | ... MFMA(mh1,ks0) ...
//  p3:                                STG A0(kt+2)  | ... MFMA(mh0,ks1) ...
//  p4:                                STG A1(kt+2)  | ... MFMA(mh1,ks1) vmcnt(4) bar
//  p5..p8: same on buf1, staging B0/B1(kt+2), A0/A1(kt+3), vmcnt(4) at p8.
// Ledger (verified): at p4-wait outstanding = [A0(kt+1),A1(kt+1),B0(kt+1),
// B1(kt+1),A0(kt+2)@p3,A1(kt+2)@p4] -> vmcnt(4) certifies kt+1 (used p5);
// at p8-wait certifies kt+2 (used next p1). Reads batched in p1/p2 so all
// 4 subtiles of a buf are free from p3 -> 1 half-tile staged per phase.
// Tail: last iter (kt 14,15) stages only B0/B1(15) at p1/p2; vmcnt(0) @p4.
// =====================================================================
#define AHTO(buf, h) ((buf) * 16384 + (h) * 8192)
#define BHTO(buf, h) (32768 + (buf) * 16384 + (h) * 8192)

#define STG_A(buf, h, kt)                                                    \
  {                                                                          \
    gload_lds16(A + (long)((h) * 128 + w * 8 + srl) * DD + (kt) * 64 + sch8, \
                sm + AHTO(buf, h) + w * 512);                                \
    gload_lds16(                                                             \
        A + (long)((h) * 128 + 64 + w * 8 + srl) * DD + (kt) * 64 + sch8,    \
        sm + AHTO(buf, h) + 4096 + w * 512);                                 \
  }
#define STG_B(buf, h, kt)                                                    \
  {                                                                          \
    gload_lds16(B + (long)((h) * 128 + w * 8 + srl) * DD + (kt) * 64 + sch8, \
                sm + BHTO(buf, h) + w * 512);                                \
    gload_lds16(                                                             \
        B + (long)((h) * 128 + 64 + w * 8 + srl) * DD + (kt) * 64 + sch8,    \
        sm + BHTO(buf, h) + 4096 + w * 512);                                 \
  }

#define RDA(buf, ks, dst)                                                    \
  _Pragma("unroll") for (int mf_ = 0; mf_ < 8; mf_++) dst[mf_] =             \
      *(const bf16x8*)(sm + ((aoff + (buf) * 16384 + mf_ * 1024) ^           \
                             ((ks) * 32)));
#define RDB(buf, ks, dst)                                                    \
  _Pragma("unroll") for (int nf_ = 0; nf_ < 4; nf_++) dst[nf_] =             \
      *(const bf16x8*)(sm + ((boff + (buf) * 16384 + nf_ * 1024) ^           \
                             ((ks) * 32)));

#define MF16(mh, ra_, rb_)                                                   \
  _Pragma("unroll") for (int mf_ = 0; mf_ < 4; mf_++)                        \
      _Pragma("unroll") for (int nf_ = 0; nf_ < 4; nf_++)                    \
          acc[(mh) * 4 + mf_][nf_] =                                         \
      __builtin_amdgcn_mfma_f32_16x16x32_bf16(ra_[(mh) * 4 + mf_], rb_[nf_], \
                                              acc[(mh) * 4 + mf_][nf_], 0,  \
                                              0, 0);

#define PH_OPEN                                                              \
  __builtin_amdgcn_s_barrier();                                              \
  asm volatile("s_waitcnt lgkmcnt(0)" ::: "memory");                         \
  __builtin_amdgcn_sched_barrier(0);                                         \
  __builtin_amdgcn_s_setprio(1);
#define PH_CLOSE(W)                                                          \
  __builtin_amdgcn_s_setprio(0);                                             \
  __builtin_amdgcn_sched_barrier(0);                                         \
  if ((W) == 4) asm volatile("s_waitcnt vmcnt(4)" ::: "memory");             \
  if ((W) == 0) asm volatile("s_waitcnt vmcnt(0)" ::: "memory");             \
  __builtin_amdgcn_s_barrier();                                              \
  __builtin_amdgcn_sched_barrier(0);

#define ITER8(kt0, DOS, DOT, W4, W8)                                         \
  {                                                                          \
    RDA(0, 0, ra0) RDB(0, 0, rb0) STG_B(1, 0, (kt0) + 1);                    \
    PH_OPEN MF16(0, ra0, rb0) PH_CLOSE(-1)                                   \
    RDA(0, 1, ra1) RDB(0, 1, rb1) STG_B(1, 1, (kt0) + 1);                    \
    PH_OPEN MF16(1, ra0, rb0) PH_CLOSE(-1)                                   \
    if (DOS) STG_A(0, 0, (kt0) + 2);                                         \
    PH_OPEN MF16(0, ra1, rb1) PH_CLOSE(-1)                                   \
    if (DOS) STG_A(0, 1, (kt0) + 2);                                         \
    PH_OPEN MF16(1, ra1, rb1) PH_CLOSE(W4)                                   \
    RDA(1, 0, ra0) RDB(1, 0, rb0);                                           \
    if (DOS) STG_B(0, 0, (kt0) + 2);                                         \
    PH_OPEN MF16(0, ra0, rb0) PH_CLOSE(-1)                                   \
    RDA(1, 1, ra1) RDB(1, 1, rb1);                                           \
    if (DOS) STG_B(0, 1, (kt0) + 2);                                         \
    PH_OPEN MF16(1, ra0, rb0) PH_CLOSE(-1)                                   \
    if (DOT) STG_A(1, 0, (kt0) + 3);                                         \
    PH_OPEN MF16(0, ra1, rb1) PH_CLOSE(-1)                                   \
    if (DOT) STG_A(1, 1, (kt0) + 3);                                         \
    PH_OPEN MF16(1, ra1, rb1) PH_CLOSE(W8)                                   \
  }

__global__ __launch_bounds__(512, 2) void gemm256_8ph(
    const bf16* __restrict__ Ag, const bf16* __restrict__ Bg,
    bf16* __restrict__ Cg, const float* __restrict__ bias,
    bf16* __restrict__ vTp) {
  extern __shared__ __align__(16) char dsm_[];
  bf16* sm = (bf16*)dsm_;

  // XCD-chunked bijective swizzle: 384 blocks -> 48/XCD as 6bx x 8by
  // (B slice 3 MiB L2-resident, A strips reused 6x within chunk).
  int id = (int)blockIdx.y * 12 + (int)blockIdx.x;
  int wg = (id & 7) * 48 + (id >> 3);
  int ck = wg / 48, r48 = wg % 48;
  int bx = (ck & 1) * 6 + r48 % 6;
  int by = (ck >> 1) * 8 + r48 / 6;
  long m0 = (long)by * 256, n0 = (long)bx * 256;
  const bf16* A = Ag + m0 * DD;
  const bf16* B = Bg + n0 * DD;

  int t = threadIdx.x;
  int w = t >> 6, l = t & 63;
  int wm = w >> 2, wn = w & 3;  // 2M x 4N waves, per-wave 128m x 64n
  int ln = l & 15, quad = l >> 4;

  // fragment-read offsets (elements); ks1 = ks0 XOR 32 (chunk bit2)
  int csw = (quad ^ (ln & 7)) * 8;
  uint aoff = (uint)(wm * 8192 + ln * 64 + csw);
  uint boff = (uint)(32768 + (wn >> 1) * 8192 + ((wn & 1) * 64 + ln) * 64 +
                     csw);
  // staging source decomposition (per 64-row piece): row = w*8+srl,
  // source chunk = (l&7)^srl (inverse swizzle)
  int srl = l >> 3;
  int sch8 = ((l & 7) ^ srl) * 8;

  f32x4 acc[8][4];
#pragma unroll
  for (int i = 0; i < 8; i++)
#pragma unroll
    for (int j = 0; j < 4; j++) acc[i][j] = f32x4{0.f, 0.f, 0.f, 0.f};
  bf16x8 ra0[8], ra1[8], rb0[4], rb1[4];

  // prologue: kt0 full + kt1 A-halves; vmcnt(4) certifies kt0, leaves A(kt1)
  STG_A(0, 0, 0); STG_A(0, 1, 0);
  STG_B(0, 0, 0); STG_B(0, 1, 0);
  STG_A(1, 0, 1); STG_A(1, 1, 1);
  asm volatile("s_waitcnt vmcnt(4)" ::: "memory");
  __builtin_amdgcn_s_barrier();
  __builtin_amdgcn_sched_barrier(0);

  // K=1024 -> 16 K-tiles of 64 -> 8 iterations; last peeled (no S/T stages)
#pragma unroll 1
  for (int I = 0; I < 7; ++I) {
    int kt0 = 2 * I;
    ITER8(kt0, 1, 1, 4, 4)
  }
  ITER8(14, 0, 0, 0, -1)

  __syncthreads();  // reuse sm as the epilogue bounce buffer

  // ---- epilogue: row = wm*128 + mf*16 + quad*4 + r ; col = wn*64+nf*16+ln
  if (n0 < 2048) {
    bf16* C = Cg + m0 * 3072 + n0;
#pragma unroll
    for (int mf = 0; mf < 8; mf++) {
      int rb = wm * 128 + mf * 16 + quad * 4;
#pragma unroll
      for (int nf = 0; nf < 4; nf++) {
        int col = wn * 64 + nf * 16 + ln;
        float bv_ = bias[n0 + col];
#pragma unroll
        for (int r = 0; r < 4; r++)
          C[(long)(rb + r) * 3072 + col] = (bf16)(acc[mf][nf][r] + bv_);
      }
    }
  } else {
    // V region: bounce [256 d][256 s] (128 KB) -> vT[b][d][s]
    int d0 = (int)n0 - 2048;
    int b = (int)(m0 >> 11);
    int s0 = (int)(m0 & 2047);
#pragma unroll
    for (int mf = 0; mf < 8; mf++) {
      int sl = wm * 128 + mf * 16 + quad * 4;
#pragma unroll
      for (int nf = 0; nf < 4; nf++) {
        int d = wn * 64 + nf * 16 + ln;
        float bv_ = bias[n0 + d];
#pragma unroll
        for (int r = 0; r < 4; r++)
          sm[d * 256 + ((sl + r) ^ ((d & 7) << 3))] =
              (bf16)(acc[mf][nf][r] + bv_);
      }
    }
    __syncthreads();
    int d = t >> 1, sh = t & 1;
    bf16* dst = vTp + (long)b * DD * SS + (long)(d0 + d) * SS + s0 + sh * 128;
#pragma unroll
    for (int c = 0; c < 16; ++c) {
      int sc = (sh * 128 + c * 8) ^ ((d & 7) << 3);
      *(bf16x8*)(dst + c * 8) = *(const bf16x8*)(sm + d * 256 + sc);
    }
  }
}

// =====================================================================
// scores256: causal scores + fused exp (QTILE structure, BK=32, 64KB LDS).
// =====================================================================
#define CSTGA(pa, kt)                                                        \
  gload_lds16(Aq + (long)(w * 16 + srow) * 3072 + (kt) * 32 + scg,           \
              As + (pa) * 4096 + w * 512)
#define CSTGB(pb, h, kt)                                                     \
  gload_lds16(Bk + (long)((h) * 128 + w * 16 + srow) * 3072 + (kt) * 32 +    \
                  scg,                                                       \
              Bs + (pb) * 8192 + (h) * 4096 + w * 512)

#define CTILE(pa, pb, pa1, pb2, kA, kB, DOA, DOB, WAITN)                     \
  {                                                                          \
    bf16x8 af[4], bfr[4];                                                    \
    _Pragma("unroll") for (int i_ = 0; i_ < 4; i_++)                         \
        af[i_] = *(const bf16x8*)(a_base + (pa) * 4096 + i_ * 512);          \
    _Pragma("unroll") for (int j_ = 0; j_ < 4; j_++)                         \
        bfr[j_] = *(const bf16x8*)(b_base + (pb) * 8192 + j_ * 512);         \
    if (DOA) { CSTGA(pa1, kA); }                                             \
    if (DOB) { CSTGB(pb2, 0, kB); CSTGB(pb2, 1, kB); }                       \
    __builtin_amdgcn_s_barrier();                                            \
    asm volatile("s_waitcnt lgkmcnt(0)" ::: "memory");                       \
    __builtin_amdgcn_sched_barrier(0);                                       \
    __builtin_amdgcn_s_setprio(1);                                           \
    _Pragma("unroll") for (int i_ = 0; i_ < 4; i_++)                         \
        _Pragma("unroll") for (int j_ = 0; j_ < 4; j_++) acc[i_][j_] =       \
        __builtin_amdgcn_mfma_f32_16x16x32_bf16(af[i_], bfr[j_],             \
                                                acc[i_][j_], 0, 0, 0);       \
    __builtin_amdgcn_s_setprio(0);                                           \
    __builtin_amdgcn_sched_barrier(0);                                       \
    if ((WAITN) == 2) asm volatile("s_waitcnt vmcnt(2)" ::: "memory");       \
    if ((WAITN) == 0) asm volatile("s_waitcnt vmcnt(0)" ::: "memory");       \
    __builtin_amdgcn_s_barrier();                                            \
    __builtin_amdgcn_sched_barrier(0);                                       \
  }

__global__ __launch_bounds__(512, 4) void scores256(
    const bf16* __restrict__ qkvp, bf16* __restrict__ P,
    float* __restrict__ rowsums) {
  __shared__ __align__(16) bf16 smem[32768];
  bf16* As = smem;
  bf16* Bs = smem + 8192;

  int bz = blockIdx.z;
  int id = (int)blockIdx.x;
  int q = (id & 7) * 9 + (id >> 3);
  int s = (int)sqrtf((float)q + 0.5f);
  while (s * s > q) s--;
  while ((s + 1) * (s + 1) <= q) s++;
  int by, bxc;
  if (q >= s * (s + 1)) { by = 2 * s; bxc = q - s * (s + 1); }
  else { by = 2 * s - 1; bxc = q - s * s; }
  long m0 = (long)by * 128, n0 = (long)bxc * 256;
  const bf16* Aq = qkvp + (long)bz * SS * 3072 + m0 * 3072;
  const bf16* Bk = qkvp + 1024 + (long)bz * SS * 3072 + n0 * 3072;

  int t = threadIdx.x;
  int w = t >> 6, l = t & 63;
  int wm = w >> 2, wn = w & 3;
  int ln = l & 15, quad = l >> 4;

  int srow = l >> 2;
  int scg = ((l & 3) ^ ((l >> 3) & 3)) * 8;
  int rdslot = (quad ^ ((ln >> 1) & 3)) * 8;
  const bf16* a_base = As + (wm * 64 + ln) * 32 + rdslot;
  const bf16* b_base = Bs + (wn * 64 + ln) * 32 + rdslot;

  f32x4 acc[4][4];
#pragma unroll
  for (int i = 0; i < 4; i++)
#pragma unroll
    for (int j = 0; j < 4; j++) acc[i][j] = f32x4{0.f, 0.f, 0.f, 0.f};

  CSTGA(0, 0);
  CSTGB(0, 0, 0); CSTGB(0, 1, 0);
  CSTGB(1, 0, 1); CSTGB(1, 1, 1);
  asm volatile("s_waitcnt vmcnt(2)" ::: "memory");
  __builtin_amdgcn_s_barrier();
  __builtin_amdgcn_sched_barrier(0);
#pragma unroll 1
  for (int t6 = 0; t6 < 30; t6 += 6) {
    CTILE(0, 0, 1, 2, t6 + 1, t6 + 2, 1, 1, 2)
    CTILE(1, 1, 0, 0, t6 + 2, t6 + 3, 1, 1, 2)
    CTILE(0, 2, 1, 1, t6 + 3, t6 + 4, 1, 1, 2)
    CTILE(1, 0, 0, 2, t6 + 4, t6 + 5, 1, 1, 2)
    CTILE(0, 1, 1, 0, t6 + 5, t6 + 6, 1, 1, 2)
    CTILE(1, 2, 0, 1, t6 + 6, t6 + 7, 1, 1, 2)
  }
  CTILE(0, 0, 1, 0, 31, 0, 1, 0, 0)
  CTILE(1, 1, 0, 0, 0, 0, 0, 0, -1)

  __syncthreads();

#pragma unroll
  for (int i = 0; i < 4; i++) {
    int rb = wm * 64 + i * 16 + quad * 4;
#pragma unroll
    for (int j = 0; j < 4; j++) {
      int col = wn * 64 + j * 16 + ln;
#pragma unroll
      for (int r = 0; r < 4; r++) {
        int row = rb + r;
        float p = 0.f;
        if (n0 + col <= m0 + row) p = __expf(acc[i][j][r] * 0.03125f);
        smem[row * 256 + (col ^ ((row & 7) << 3))] = (bf16)p;
      }
    }
  }
  __syncthreads();
  int row = t >> 2, qtr = t & 3;
  bf16* Pr = P + (long)bz * SS * SS + (m0 + row) * SS + n0;
  float rsum = 0.f;
#pragma unroll
  for (int c8 = 0; c8 < 8; c8++) {
    int p8 = qtr * 8 + c8;
    int slot = p8 ^ (row & 7);
    bf16x8 v = *(const bf16x8*)(smem + row * 256 + slot * 8);
#pragma unroll
    for (int e = 0; e < 8; e++) rsum += (float)v[e];
    *(bf16x8*)(Pr + p8 * 8) = v;
  }
  rsum += __shfl_xor(rsum, 1, 64);
  rsum += __shfl_xor(rsum, 2, 64);
  if (qtr == 0) atomicAdd(&rowsums[(long)bz * SS + m0 + row], rsum);
}

// ---- generic bf16 GEMM: 128x128 tiles (fold / PV) ----------------------
template <int MODE>
__global__ __launch_bounds__(256, 4)
void gemm_bt(const bf16* __restrict__ Ag, long lda, long sAb,
             const bf16* __restrict__ Bg, long ldb, long sBb,
             void* __restrict__ Cg, long ldc, long sCb,
             const float* __restrict__ bias, float scale, int K,
             bf16* __restrict__ vTp, float* __restrict__ rowsums) {
  __shared__ __align__(16) bf16 smem[16384];  // As | Bs
  bf16* As = smem;
  bf16* Bs = smem + 8192;

  int bx = blockIdx.x, by = blockIdx.y, bz = blockIdx.z;
  if (MODE == 0) {
    int nx = (int)gridDim.x;
    int nwg = nx * (int)gridDim.y;
    int id = by * nx + bx;
    int xcd = id & 7, rest = id >> 3;
    int q8 = nwg >> 3, r8 = nwg & 7;
    int wg = (xcd < r8 ? xcd * (q8 + 1) : r8 * (q8 + 1) + (xcd - r8) * q8)
             + rest;
    bx = wg % nx;
    by = wg / nx;
  }
  if (MODE == 2) by = 15 - by;  // longest K strips dispatch first
  long m0 = (long)by * 128, n0 = (long)bx * 128;
  const bf16* A = Ag + (long)bz * sAb + m0 * lda;
  const bf16* Bp = Bg + (long)bz * sBb + n0 * ldb;

  int t = threadIdx.x;
  int w = t >> 6, l = t & 63;
  int lr = l >> 2;
  int lc = (((l & 3) ^ (lr & 3)) * 8);
  int quad = l >> 4, ln = l & 15;
  int wm = w >> 1, wn = w & 1;
  int rdoff = ((quad ^ (ln & 3)) * 8);

  int Keff = (MODE == 2) ? (by + 1) * 128 : K;

  f32x4 acc[4][4];
#pragma unroll
  for (int i = 0; i < 4; i++)
#pragma unroll
    for (int j = 0; j < 4; j++) acc[i][j] = f32x4{0.f, 0.f, 0.f, 0.f};

  const bf16* a_base = As + (wm * 64 + ln) * 32 + rdoff;
  const bf16* b_base = Bs + (wn * 64 + ln) * 32 + rdoff;
  long arow0 = (long)(w * 16 + lr);

#define STG(p, kc0)                                                         \
  {                                                                         \
    int kc = (kc0) + lc;                                                    \
    gload_lds16(A + arow0 * lda + kc, As + (p) * 4096 + w * 512);           \
    gload_lds16(A + (arow0 + 64) * lda + kc,                                \
                As + (p) * 4096 + 2048 + w * 512);                          \
    gload_lds16(Bp + arow0 * ldb + kc, Bs + (p) * 4096 + w * 512);          \
    gload_lds16(Bp + (arow0 + 64) * ldb + kc,                               \
                Bs + (p) * 4096 + 2048 + w * 512);                          \
  }

  STG(0, 0);
  int cur = 0;
  for (int k = 0; k < Keff; k += 32) {
    asm volatile("s_waitcnt vmcnt(0)" ::: "memory");
    __builtin_amdgcn_s_barrier();
    __builtin_amdgcn_sched_barrier(0);
    if (k + 32 < Keff) STG(cur ^ 1, k + 32);
    bf16x8 af[4], bfr[4];
#pragma unroll
    for (int i = 0; i < 4; i++) {
      af[i] = *(const bf16x8*)(a_base + cur * 4096 + i * 512);
      bfr[i] = *(const bf16x8*)(b_base + cur * 4096 + i * 512);
    }
#pragma unroll
    for (int i = 0; i < 4; i++)
#pragma unroll
      for (int j = 0; j < 4; j++)
        acc[i][j] = __builtin_amdgcn_mfma_f32_16x16x32_bf16(
            af[i], bfr[j], acc[i][j], 0, 0, 0);
    cur ^= 1;
  }
#undef STG
  __syncthreads();

  if (MODE == 0) {
    bf16* C = (bf16*)Cg + (long)bz * sCb + m0 * ldc + n0;
#pragma unroll
    for (int i = 0; i < 4; i++) {
      int rb = wm * 64 + i * 16 + quad * 4;
#pragma unroll
      for (int j = 0; j < 4; j++) {
        int col = wn * 64 + j * 16 + ln;
        float bv_ = bias ? bias[n0 + col] : 0.f;
#pragma unroll
        for (int r = 0; r < 4; r++)
          C[(long)(rb + r) * ldc + col] = (bf16)(acc[i][j][r] + bv_);
      }
    }
  } else {
    float* C = (float*)Cg + (long)bz * sCb + m0 * ldc + n0;
    const float* rs = rowsums + (long)bz * SS + m0;
#pragma unroll
    for (int i = 0; i < 4; i++) {
      int rb = wm * 64 + i * 16 + quad * 4;
      float inv[4];
#pragma unroll
      for (int r = 0; r < 4; r++) inv[r] = 1.f / rs[rb + r];
#pragma unroll
      for (int j = 0; j < 4; j++) {
        int col = wn * 64 + j * 16 + ln;
#pragma unroll
        for (int r = 0; r < 4; r++)
          C[(long)(rb + r) * ldc + col] = acc[i][j][r] * inv[r];
      }
    }
  }
}

extern "C" void kernel_launch(void* const* d_in, const int* in_sizes, int n_in,
                              void* d_out, int out_size, void* d_ws,
                              size_t ws_size, hipStream_t stream) {
  const float* x = (const float*)d_in[0];
  const float* R = (const float*)d_in[1];
  const float* E = (const float*)d_in[2];
  const float* Wq = (const float*)d_in[3];
  const float* bq = (const float*)d_in[4];
  const float* Wk = (const float*)d_in[5];
  const float* bk = (const float*)d_in[6];
  const float* Wv = (const float*)d_in[7];
  const float* bv = (const float*)d_in[8];
  float* out = (float*)d_out;

  char* ws = (char*)d_ws;
  bf16* qkv = (bf16*)ws;
  bf16* vT = (bf16*)(ws + 50331648);
  bf16* probs = (bf16*)(ws + 67108864);
  float* rowsums = (float*)(ws + 100663296);
  char* sr = ws + 101711872;
  bf16* xb = (bf16*)sr;                   // 16 MiB
  bf16* Rb = (bf16*)(sr + 16777216);      // 2 MiB
  bf16* Eb = Rb + 1024 * 1024;            // 2 MiB
  bf16* WqT = (bf16*)(sr + 20971520);     // 2 MiB
  bf16* WkT = WqT + 1024 * 1024;          // 2 MiB
  bf16* wcat = (bf16*)(sr + 25165824);    // 6 MiB (Wq'|Wk'|Wv)
  float* bias = (float*)(sr + 31457280);  // 12 KiB

  // allow 128 KiB dynamic LDS for the 8-phase QKV kernel (host-side
  // attribute set; not a stream op -> graph-capture safe)
  (void)hipFuncSetAttribute(reinterpret_cast<const void*>(gemm256_8ph),
                            hipFuncAttributeMaxDynamicSharedMemorySize,
                            131072);

  // 1) all preprocessing + rowsum zeroing: 1 dispatch
  prep_all<<<16416, 256, 0, stream>>>(x, R, E, Wv, Wq, Wk, bq, bk, bv, xb, Rb,
                                      Eb, wcat + 2048 * DD, WqT, WkT, bias,
                                      rowsums);

  // 2) fold weights (batched bz=2): Wq' = R@Wq ; Wk' = E@Wk
  gemm_bt<0><<<dim3(8, 8, 2), 256, 0, stream>>>(
      Rb, DD, 1024 * 1024, WqT, DD, 1024 * 1024, wcat, DD, 1024 * 1024,
      nullptr, 1.f, DD, nullptr, nullptr);

  // 3) fused QKV (M=8192, N=3072, K=1024), 256x256 tiles, m201 8-phase;
  //    V-tiles written transposed to vT
  gemm256_8ph<<<dim3(12, 32, 1), 512, 131072, stream>>>(xb, wcat, qkv, bias,
                                                        vT);

  // 4) causal scores + fused exp -> bf16 probs + row sums
  scores256<<<dim3(72, 1, BB), 512, 0, stream>>>(qkv, probs, rowsums);

  // 5) out = (P~ @ V) / rowsum : K truncated causally, long strips first
  gemm_bt<2><<<dim3(8, 16, BB), 256, 0, stream>>>(
      probs, SS, (long)SS * SS, vT, SS, (long)DD * SS, out,
      DD, (long)SS * DD, nullptr, 1.f, SS, nullptr, rowsums);
}

// Round 7
// 288.064 us; speedup vs baseline: 1.1127x; 1.1127x over previous
//
#include <hip/hip_runtime.h>
#include <hip/hip_bf16.h>
#include <stdint.h>
#include <math.h>

// Problem constants
#define DD 1024
#define SS 2048
#define BB 4

typedef __bf16 bf16;
typedef __bf16 bf16x8 __attribute__((ext_vector_type(8)));
typedef __bf16 bf16x4 __attribute__((ext_vector_type(4)));
typedef float f32x4 __attribute__((ext_vector_type(4)));

// ---- async global->LDS 16B copy (dest = wave-uniform base + lane*16) ----
__device__ __forceinline__ void gload_lds16(const bf16* g, bf16* l) {
  __builtin_amdgcn_global_load_lds(
      (const __attribute__((address_space(1))) void*)g,
      (__attribute__((address_space(3))) void*)l, 16, 0, 0);
}

// ---- ALL preprocessing in ONE dispatch --------------------------------
__global__ __launch_bounds__(256) void prep_all(
    const float* __restrict__ x, const float* __restrict__ R,
    const float* __restrict__ E, const float* __restrict__ Wv,
    const float* __restrict__ Wq, const float* __restrict__ Wk,
    const float* __restrict__ bq, const float* __restrict__ bk,
    const float* __restrict__ bv, bf16* __restrict__ xb,
    bf16* __restrict__ Rb, bf16* __restrict__ Eb, bf16* __restrict__ Wvb,
    bf16* __restrict__ WqT, bf16* __restrict__ WkT, float* __restrict__ bias,
    float* __restrict__ rowsums) {
  int bid = blockIdx.x;
  int t = threadIdx.x;
  if (bid < 11264) {
    const float* src;
    bf16* dst;
    int base;
    if (bid < 8192) { src = x; dst = xb; base = bid; }
    else if (bid < 9216) { src = R; dst = Rb; base = bid - 8192; }
    else if (bid < 10240) { src = E; dst = Eb; base = bid - 9216; }
    else { src = Wv; dst = Wvb; base = bid - 10240; }
    int i = (base * 256 + t) * 4;
    float4 v = *(const float4*)(src + i);
    bf16x4 o;
    o.x = (bf16)v.x; o.y = (bf16)v.y; o.z = (bf16)v.z; o.w = (bf16)v.w;
    *(bf16x4*)(dst + i) = o;
  } else if (bid < 13312) {
    int r2 = bid - 11264;
    const float* src = (r2 >= 1024) ? Wk : Wq;
    bf16* dst = (r2 >= 1024) ? WkT : WqT;
    int rem = r2 & 1023;
    int bx = rem & 31, by = rem >> 5;
    __shared__ float tile[32][33];
    int tx = t & 31, ty = t >> 5;
    int xcol = bx * 32 + tx;
    int y0 = by * 32;
    for (int r = ty; r < 32; r += 8)
      tile[r][tx] = src[(y0 + r) * DD + xcol];
    __syncthreads();
    int dx = by * 32 + tx;
    int dy0 = bx * 32;
    for (int r = ty; r < 32; r += 8)
      dst[(dy0 + r) * DD + dx] = (bf16)tile[tx][r];
  } else if (bid < 16384) {
    int e = bid - 13312;  // 0..3071
    if (e >= 2048) { if (t == 0) bias[e] = bv[e - 2048]; return; }
    const float* M = (e < 1024) ? R : E;
    const float* bb = (e < 1024) ? bq : bk;
    int row = e & 1023;
    float s = 0.f;
    for (int f = t; f < DD; f += 256) s += M[row * DD + f] * bb[f];
    for (int o = 32; o >= 1; o >>= 1) s += __shfl_xor(s, o, 64);
    __shared__ float red[4];
    if ((t & 63) == 0) red[t >> 6] = s;
    __syncthreads();
    if (t == 0) bias[e] = red[0] + red[1] + red[2] + red[3];
  } else {
    int idx = (bid - 16384) * 256 + t;  // 0..8191
    rowsums[idx] = 0.f;
  }
}

// =====================================================================
// gemm_qkv_rp: 128x128-tile GEMM with REGISTER-PREFETCHED fragments and
// ONE barrier per K-tile (BK=32). C = A @ B^T (+bias), A=xb, B=wcat,
// C=qkv (ldc 3072); V-region tiles (n0>=2048) -> vT transposed bounce.
// 4 waves (2Mx2N, per-wave 64x64, acc[4][4]). LDS 32KB: As[2][128][32],
// Bs[2][128][32]. ~150 VGPR -> 12 waves/CU = 3 blocks/CU (TLP across
// blocks fills barrier gaps). Grid 24x64 = 1536 = 2 exact rounds.
//
// iter t (tile t in buf[t&1]; frags(t) ALREADY in registers):
//   1. lgkmcnt(0)   -- own frag-reads of tile t retired
//   2. vmcnt(0)     -- own stage(t+1) loads landed (only ones in flight)
//   3. s_barrier    -- globalizes 1+2: reads(t) all retired, stage(t+1)
//                      visible -> buf[t&1] overwritable, buf[(t+1)&1] valid
//   4. ds_read frags(t+1) from buf[(t+1)&1]   (8 x b128)
//   5. stage(t+2) -> buf[t&1]                 (4 x gload_lds)
//   6. MFMA(t) from registers -- NO LDS WAIT on critical path; reads (4)
//      and stage (5) latency hide under ~258 cyc of MFMA.
// Race-free: overwrite of buf[t&1] (5) happens only after (1)+(3) proved
// every wave's reads of tile t retired. vmcnt(0) at (2) waits a load
// issued one full MFMA phase earlier (~300+ cyc cover).
// Tail: t=30 reads frags(31), no stage; t=31 pure MFMA.
// =====================================================================
#define RPSTG(p, kt)                                                         \
  {                                                                          \
    int kc = (kt) * 32 + lc;                                                 \
    gload_lds16(A + arow0 * DD + kc, As + (p) * 4096 + w * 512);             \
    gload_lds16(A + (arow0 + 64) * DD + kc,                                  \
                As + (p) * 4096 + 2048 + w * 512);                           \
    gload_lds16(B + arow0 * DD + kc, Bs + (p) * 4096 + w * 512);             \
    gload_lds16(B + (arow0 + 64) * DD + kc,                                  \
                Bs + (p) * 4096 + 2048 + w * 512);                           \
  }

#define RPRD(a_, b_, p)                                                      \
  _Pragma("unroll") for (int i_ = 0; i_ < 4; i_++) {                         \
    a_[i_] = *(const bf16x8*)(a_base + (p) * 4096 + i_ * 512);               \
    b_[i_] = *(const bf16x8*)(b_base + (p) * 4096 + i_ * 512);               \
  }

#define RPMM(a_, b_)                                                         \
  _Pragma("unroll") for (int i_ = 0; i_ < 4; i_++)                           \
      _Pragma("unroll") for (int j_ = 0; j_ < 4; j_++) acc[i_][j_] =         \
      __builtin_amdgcn_mfma_f32_16x16x32_bf16(a_[i_], b_[j_],                \
                                              acc[i_][j_], 0, 0, 0);

#define RPITER(aC, bC, aN, bN, t)                                            \
  {                                                                          \
    asm volatile("s_waitcnt lgkmcnt(0)" ::: "memory");                       \
    asm volatile("s_waitcnt vmcnt(0)" ::: "memory");                         \
    __builtin_amdgcn_sched_barrier(0);                                       \
    __builtin_amdgcn_s_barrier();                                            \
    __builtin_amdgcn_sched_barrier(0);                                       \
    RPRD(aN, bN, ((t) + 1) & 1)                                              \
    RPSTG((t) & 1, (t) + 2)                                                  \
    RPMM(aC, bC)                                                             \
  }

__global__ __launch_bounds__(256, 3) void gemm_qkv_rp(
    const bf16* __restrict__ Ag, const bf16* __restrict__ Bg,
    bf16* __restrict__ Cg, const float* __restrict__ bias,
    bf16* __restrict__ vTp) {
  __shared__ __align__(16) bf16 smem[16384];  // As[2][128][32] | Bs[2][...]
  bf16* As = smem;
  bf16* Bs = smem + 8192;

  // XCD-chunked bijective swizzle: 1536 blocks -> 192/XCD in 4bx x 8by
  // sub-chunks (B slice 1 MiB + A strips 2 MiB L2-resident).
  int id = (int)blockIdx.y * 24 + (int)blockIdx.x;
  int wg = (id & 7) * 192 + (id >> 3);
  int xcd = wg / 192, r = wg % 192;
  int bxg = r >> 5, rr = r & 31;
  int bx = bxg * 4 + (rr & 3);
  int by = xcd * 8 + (rr >> 2);
  long m0 = (long)by * 128, n0 = (long)bx * 128;
  const bf16* A = Ag + m0 * DD;
  const bf16* B = Bg + n0 * DD;

  int t = threadIdx.x;
  int w = t >> 6, l = t & 63;
  int lr = l >> 2;
  int lc = (((l & 3) ^ (lr & 3)) * 8);  // inverse-swizzled source chunk
  int quad = l >> 4, ln = l & 15;
  int wm = w >> 1, wn = w & 1;          // 2M x 2N waves, per-wave 64x64
  int rdoff = ((quad ^ (ln & 3)) * 8);  // swizzled read offset
  long arow0 = (long)(w * 16 + lr);

  const bf16* a_base = As + (wm * 64 + ln) * 32 + rdoff;
  const bf16* b_base = Bs + (wn * 64 + ln) * 32 + rdoff;

  f32x4 acc[4][4];
#pragma unroll
  for (int i = 0; i < 4; i++)
#pragma unroll
    for (int j = 0; j < 4; j++) acc[i][j] = f32x4{0.f, 0.f, 0.f, 0.f};

  bf16x8 aA[4], bA[4], aB[4], bB[4];

  // prologue: stage tiles 0,1; certify 0; read frags(0) into set A
  RPSTG(0, 0)
  RPSTG(1, 1)
  asm volatile("s_waitcnt vmcnt(4)" ::: "memory");
  __builtin_amdgcn_s_barrier();
  __builtin_amdgcn_sched_barrier(0);
  RPRD(aA, bA, 0)

  // K=1024 -> 32 tiles; loop covers t=0..29 (stages through tile 31)
#pragma unroll 1
  for (int t2 = 0; t2 < 30; t2 += 2) {
    RPITER(aA, bA, aB, bB, t2)
    RPITER(aB, bB, aA, bA, t2 + 1)
  }
  // t=30: certify stage(31), read frags(31), no stage, MFMA(30)
  asm volatile("s_waitcnt lgkmcnt(0)" ::: "memory");
  asm volatile("s_waitcnt vmcnt(0)" ::: "memory");
  __builtin_amdgcn_sched_barrier(0);
  __builtin_amdgcn_s_barrier();
  __builtin_amdgcn_sched_barrier(0);
  RPRD(aB, bB, 1)
  RPMM(aA, bA)
  // t=31: pure MFMA (compiler inserts lgkm wait for aB/bB deps)
  RPMM(aB, bB)

  __syncthreads();  // epilogue may reuse smem as a bounce buffer

  // ---- epilogue: row = wm*64 + i*16 + quad*4 + r, col = wn*64 + j*16 + ln
  if (n0 < 2048) {
    bf16* C = Cg + m0 * 3072 + n0;
#pragma unroll
    for (int i = 0; i < 4; i++) {
      int rb = wm * 64 + i * 16 + quad * 4;
#pragma unroll
      for (int j = 0; j < 4; j++) {
        int col = wn * 64 + j * 16 + ln;
        float bv_ = bias[n0 + col];
#pragma unroll
        for (int r = 0; r < 4; r++)
          C[(long)(rb + r) * 3072 + col] = (bf16)(acc[i][j][r] + bv_);
      }
    }
  } else {
    // V region: bounce to smem[128 d][128 s], write vT[b][d][s]
    int d0 = (int)n0 - 2048;
    int b = (int)(m0 >> 11);
    int s0 = (int)(m0 & 2047);
#pragma unroll
    for (int i = 0; i < 4; i++) {
      int sl = wm * 64 + i * 16 + quad * 4;
#pragma unroll
      for (int j = 0; j < 4; j++) {
        int d = wn * 64 + j * 16 + ln;
        float bv_ = bias[n0 + d];
#pragma unroll
        for (int r = 0; r < 4; r++)
          smem[d * 128 + ((sl + r) ^ ((d & 7) << 3))] =
              (bf16)(acc[i][j][r] + bv_);
      }
    }
    __syncthreads();
    int d = t >> 1, sh = t & 1;
    bf16* dst = vTp + (long)b * DD * SS + (long)(d0 + d) * SS + s0 + sh * 64;
#pragma unroll
    for (int c = 0; c < 8; ++c) {
      int sc = (sh * 64 + c * 8) ^ ((d & 7) << 3);
      *(bf16x8*)(dst + c * 8) = *(const bf16x8*)(smem + d * 128 + sc);
    }
  }
}

// =====================================================================
// scores256: causal scores + fused exp (QTILE structure, BK=32, 64KB LDS).
// =====================================================================
#define CSTGA(pa, kt)                                                        \
  gload_lds16(Aq + (long)(w * 16 + srow) * 3072 + (kt) * 32 + scg,           \
              As + (pa) * 4096 + w * 512)
#define CSTGB(pb, h, kt)                                                     \
  gload_lds16(Bk + (long)((h) * 128 + w * 16 + srow) * 3072 + (kt) * 32 +    \
                  scg,                                                       \
              Bs + (pb) * 8192 + (h) * 4096 + w * 512)

#define CTILE(pa, pb, pa1, pb2, kA, kB, DOA, DOB, WAITN)                     \
  {                                                                          \
    bf16x8 af[4], bfr[4];                                                    \
    _Pragma("unroll") for (int i_ = 0; i_ < 4; i_++)                         \
        af[i_] = *(const bf16x8*)(a_base + (pa) * 4096 + i_ * 512);          \
    _Pragma("unroll") for (int j_ = 0; j_ < 4; j_++)                         \
        bfr[j_] = *(const bf16x8*)(b_base + (pb) * 8192 + j_ * 512);         \
    if (DOA) { CSTGA(pa1, kA); }                                             \
    if (DOB) { CSTGB(pb2, 0, kB); CSTGB(pb2, 1, kB); }                       \
    __builtin_amdgcn_s_barrier();                                            \
    asm volatile("s_waitcnt lgkmcnt(0)" ::: "memory");                       \
    __builtin_amdgcn_sched_barrier(0);                                       \
    __builtin_amdgcn_s_setprio(1);                                           \
    _Pragma("unroll") for (int i_ = 0; i_ < 4; i_++)                         \
        _Pragma("unroll") for (int j_ = 0; j_ < 4; j_++) acc[i_][j_] =       \
        __builtin_amdgcn_mfma_f32_16x16x32_bf16(af[i_], bfr[j_],             \
                                                acc[i_][j_], 0, 0, 0);       \
    __builtin_amdgcn_s_setprio(0);                                           \
    __builtin_amdgcn_sched_barrier(0);                                       \
    if ((WAITN) == 2) asm volatile("s_waitcnt vmcnt(2)" ::: "memory");       \
    if ((WAITN) == 0) asm volatile("s_waitcnt vmcnt(0)" ::: "memory");       \
    __builtin_amdgcn_s_barrier();                                            \
    __builtin_amdgcn_sched_barrier(0);                                       \
  }

__global__ __launch_bounds__(512, 4) void scores256(
    const bf16* __restrict__ qkvp, bf16* __restrict__ P,
    float* __restrict__ rowsums) {
  __shared__ __align__(16) bf16 smem[32768];
  bf16* As = smem;
  bf16* Bs = smem + 8192;

  int bz = blockIdx.z;
  int id = (int)blockIdx.x;
  int q = (id & 7) * 9 + (id >> 3);
  int s = (int)sqrtf((float)q + 0.5f);
  while (s * s > q) s--;
  while ((s + 1) * (s + 1) <= q) s++;
  int by, bxc;
  if (q >= s * (s + 1)) { by = 2 * s; bxc = q - s * (s + 1); }
  else { by = 2 * s - 1; bxc = q - s * s; }
  long m0 = (long)by * 128, n0 = (long)bxc * 256;
  const bf16* Aq = qkvp + (long)bz * SS * 3072 + m0 * 3072;
  const bf16* Bk = qkvp + 1024 + (long)bz * SS * 3072 + n0 * 3072;

  int t = threadIdx.x;
  int w = t >> 6, l = t & 63;
  int wm = w >> 2, wn = w & 3;
  int ln = l & 15, quad = l >> 4;

  int srow = l >> 2;
  int scg = ((l & 3) ^ ((l >> 3) & 3)) * 8;
  int rdslot = (quad ^ ((ln >> 1) & 3)) * 8;
  const bf16* a_base = As + (wm * 64 + ln) * 32 + rdslot;
  const bf16* b_base = Bs + (wn * 64 + ln) * 32 + rdslot;

  f32x4 acc[4][4];
#pragma unroll
  for (int i = 0; i < 4; i++)
#pragma unroll
    for (int j = 0; j < 4; j++) acc[i][j] = f32x4{0.f, 0.f, 0.f, 0.f};

  CSTGA(0, 0);
  CSTGB(0, 0, 0); CSTGB(0, 1, 0);
  CSTGB(1, 0, 1); CSTGB(1, 1, 1);
  asm volatile("s_waitcnt vmcnt(2)" ::: "memory");
  __builtin_amdgcn_s_barrier();
  __builtin_amdgcn_sched_barrier(0);
#pragma unroll 1
  for (int t6 = 0; t6 < 30; t6 += 6) {
    CTILE(0, 0, 1, 2, t6 + 1, t6 + 2, 1, 1, 2)
    CTILE(1, 1, 0, 0, t6 + 2, t6 + 3, 1, 1, 2)
    CTILE(0, 2, 1, 1, t6 + 3, t6 + 4, 1, 1, 2)
    CTILE(1, 0, 0, 2, t6 + 4, t6 + 5, 1, 1, 2)
    CTILE(0, 1, 1, 0, t6 + 5, t6 + 6, 1, 1, 2)
    CTILE(1, 2, 0, 1, t6 + 6, t6 + 7, 1, 1, 2)
  }
  CTILE(0, 0, 1, 0, 31, 0, 1, 0, 0)
  CTILE(1, 1, 0, 0, 0, 0, 0, 0, -1)

  __syncthreads();

#pragma unroll
  for (int i = 0; i < 4; i++) {
    int rb = wm * 64 + i * 16 + quad * 4;
#pragma unroll
    for (int j = 0; j < 4; j++) {
      int col = wn * 64 + j * 16 + ln;
#pragma unroll
      for (int r = 0; r < 4; r++) {
        int row = rb + r;
        float p = 0.f;
        if (n0 + col <= m0 + row) p = __expf(acc[i][j][r] * 0.03125f);
        smem[row * 256 + (col ^ ((row & 7) << 3))] = (bf16)p;
      }
    }
  }
  __syncthreads();
  int row = t >> 2, qtr = t & 3;
  bf16* Pr = P + (long)bz * SS * SS + (m0 + row) * SS + n0;
  float rsum = 0.f;
#pragma unroll
  for (int c8 = 0; c8 < 8; c8++) {
    int p8 = qtr * 8 + c8;
    int slot = p8 ^ (row & 7);
    bf16x8 v = *(const bf16x8*)(smem + row * 256 + slot * 8);
#pragma unroll
    for (int e = 0; e < 8; e++) rsum += (float)v[e];
    *(bf16x8*)(Pr + p8 * 8) = v;
  }
  rsum += __shfl_xor(rsum, 1, 64);
  rsum += __shfl_xor(rsum, 2, 64);
  if (qtr == 0) atomicAdd(&rowsums[(long)bz * SS + m0 + row], rsum);
}

// ---- generic bf16 GEMM: 128x128 tiles (fold / PV) ----------------------
template <int MODE>
__global__ __launch_bounds__(256, 4)
void gemm_bt(const bf16* __restrict__ Ag, long lda, long sAb,
             const bf16* __restrict__ Bg, long ldb, long sBb,
             void* __restrict__ Cg, long ldc, long sCb,
             const float* __restrict__ bias, float scale, int K,
             bf16* __restrict__ vTp, float* __restrict__ rowsums) {
  __shared__ __align__(16) bf16 smem[16384];  // As | Bs
  bf16* As = smem;
  bf16* Bs = smem + 8192;

  int bx = blockIdx.x, by = blockIdx.y, bz = blockIdx.z;
  if (MODE == 0) {
    int nx = (int)gridDim.x;
    int nwg = nx * (int)gridDim.y;
    int id = by * nx + bx;
    int xcd = id & 7, rest = id >> 3;
    int q8 = nwg >> 3, r8 = nwg & 7;
    int wg = (xcd < r8 ? xcd * (q8 + 1) : r8 * (q8 + 1) + (xcd - r8) * q8)
             + rest;
    bx = wg % nx;
    by = wg / nx;
  }
  if (MODE == 2) by = 15 - by;  // longest K strips dispatch first
  long m0 = (long)by * 128, n0 = (long)bx * 128;
  const bf16* A = Ag + (long)bz * sAb + m0 * lda;
  const bf16* Bp = Bg + (long)bz * sBb + n0 * ldb;

  int t = threadIdx.x;
  int w = t >> 6, l = t & 63;
  int lr = l >> 2;
  int lc = (((l & 3) ^ (lr & 3)) * 8);
  int quad = l >> 4, ln = l & 15;
  int wm = w >> 1, wn = w & 1;
  int rdoff = ((quad ^ (ln & 3)) * 8);

  int Keff = (MODE == 2) ? (by + 1) * 128 : K;

  f32x4 acc[4][4];
#pragma unroll
  for (int i = 0; i < 4; i++)
#pragma unroll
    for (int j = 0; j < 4; j++) acc[i][j] = f32x4{0.f, 0.f, 0.f, 0.f};

  const bf16* a_base = As + (wm * 64 + ln) * 32 + rdoff;
  const bf16* b_base = Bs + (wn * 64 + ln) * 32 + rdoff;
  long arow0 = (long)(w * 16 + lr);

#define STG(p, kc0)                                                         \
  {                                                                         \
    int kc = (kc0) + lc;                                                    \
    gload_lds16(A + arow0 * lda + kc, As + (p) * 4096 + w * 512);           \
    gload_lds16(A + (arow0 + 64) * lda + kc,                                \
                As + (p) * 4096 + 2048 + w * 512);                          \
    gload_lds16(Bp + arow0 * ldb + kc, Bs + (p) * 4096 + w * 512);          \
    gload_lds16(Bp + (arow0 + 64) * ldb + kc,                               \
                Bs + (p) * 4096 + 2048 + w * 512);                          \
  }

  STG(0, 0);
  int cur = 0;
  for (int k = 0; k < Keff; k += 32) {
    asm volatile("s_waitcnt vmcnt(0)" ::: "memory");
    __builtin_amdgcn_s_barrier();
    __builtin_amdgcn_sched_barrier(0);
    if (k + 32 < Keff) STG(cur ^ 1, k + 32);
    bf16x8 af[4], bfr[4];
#pragma unroll
    for (int i = 0; i < 4; i++) {
      af[i] = *(const bf16x8*)(a_base + cur * 4096 + i * 512);
      bfr[i] = *(const bf16x8*)(b_base + cur * 4096 + i * 512);
    }
#pragma unroll
    for (int i = 0; i < 4; i++)
#pragma unroll
      for (int j = 0; j < 4; j++)
        acc[i][j] = __builtin_amdgcn_mfma_f32_16x16x32_bf16(
            af[i], bfr[j], acc[i][j], 0, 0, 0);
    cur ^= 1;
  }
#undef STG
  __syncthreads();

  if (MODE == 0) {
    bf16* C = (bf16*)Cg + (long)bz * sCb + m0 * ldc + n0;
#pragma unroll
    for (int i = 0; i < 4; i++) {
      int rb = wm * 64 + i * 16 + quad * 4;
#pragma unroll
      for (int j = 0; j < 4; j++) {
        int col = wn * 64 + j * 16 + ln;
        float bv_ = bias ? bias[n0 + col] : 0.f;
#pragma unroll
        for (int r = 0; r < 4; r++)
          C[(long)(rb + r) * ldc + col] = (bf16)(acc[i][j][r] + bv_);
      }
    }
  } else {
    float* C = (float*)Cg + (long)bz * sCb + m0 * ldc + n0;
    const float* rs = rowsums + (long)bz * SS + m0;
#pragma unroll
    for (int i = 0; i < 4; i++) {
      int rb = wm * 64 + i * 16 + quad * 4;
      float inv[4];
#pragma unroll
      for (int r = 0; r < 4; r++) inv[r] = 1.f / rs[rb + r];
#pragma unroll
      for (int j = 0; j < 4; j++) {
        int col = wn * 64 + j * 16 + ln;
#pragma unroll
        for (int r = 0; r < 4; r++)
          C[(long)(rb + r) * ldc + col] = acc[i][j][r] * inv[r];
      }
    }
  }
}

extern "C" void kernel_launch(void* const* d_in, const int* in_sizes, int n_in,
                              void* d_out, int out_size, void* d_ws,
                              size_t ws_size, hipStream_t stream) {
  const float* x = (const float*)d_in[0];
  const float* R = (const float*)d_in[1];
  const float* E = (const float*)d_in[2];
  const float* Wq = (const float*)d_in[3];
  const float* bq = (const float*)d_in[4];
  const float* Wk = (const float*)d_in[5];
  const float* bk = (const float*)d_in[6];
  const float* Wv = (const float*)d_in[7];
  const float* bv = (const float*)d_in[8];
  float* out = (float*)d_out;

  char* ws = (char*)d_ws;
  bf16* qkv = (bf16*)ws;
  bf16* vT = (bf16*)(ws + 50331648);
  bf16* probs = (bf16*)(ws + 67108864);
  float* rowsums = (float*)(ws + 100663296);
  char* sr = ws + 101711872;
  bf16* xb = (bf16*)sr;                   // 16 MiB
  bf16* Rb = (bf16*)(sr + 16777216);      // 2 MiB
  bf16* Eb = Rb + 1024 * 1024;            // 2 MiB
  bf16* WqT = (bf16*)(sr + 20971520);     // 2 MiB
  bf16* WkT = WqT + 1024 * 1024;          // 2 MiB
  bf16* wcat = (bf16*)(sr + 25165824);    // 6 MiB (Wq'|Wk'|Wv)
  float* bias = (float*)(sr + 31457280);  // 12 KiB

  // 1) all preprocessing + rowsum zeroing: 1 dispatch
  prep_all<<<16416, 256, 0, stream>>>(x, R, E, Wv, Wq, Wk, bq, bk, bv, xb, Rb,
                                      Eb, wcat + 2048 * DD, WqT, WkT, bias,
                                      rowsums);

  // 2) fold weights (batched bz=2): Wq' = R@Wq ; Wk' = E@Wk
  gemm_bt<0><<<dim3(8, 8, 2), 256, 0, stream>>>(
      Rb, DD, 1024 * 1024, WqT, DD, 1024 * 1024, wcat, DD, 1024 * 1024,
      nullptr, 1.f, DD, nullptr, nullptr);

  // 3) fused QKV (M=8192, N=3072, K=1024), 128x128 reg-prefetch kernel,
  //    1536 blocks (3/CU); V-tiles written transposed to vT
  gemm_qkv_rp<<<dim3(24, 64, 1), 256, 0, stream>>>(xb, wcat, qkv, bias, vT);

  // 4) causal scores + fused exp -> bf16 probs + row sums
  scores256<<<dim3(72, 1, BB), 512, 0, stream>>>(qkv, probs, rowsums);

  // 5) out = (P~ @ V) / rowsum : K truncated causally, long strips first
  gemm_bt<2><<<dim3(8, 16, BB), 256, 0, stream>>>(
      probs, SS, (long)SS * SS, vT, SS, (long)DD * SS, out,
      DD, (long)SS * DD, nullptr, 1.f, SS, nullptr, rowsums);
}